// Round 1
// baseline (554.968 us; speedup 1.0000x reference)
//
#include <hip/hip_runtime.h>

// SNN forward: LIF -> scatter(sh) + 0.5*scatter(hh) -> LIF -> scatter(hm) -> LIF
// Constants from reference: BETA=0.9, THR=1.0, input scales 5.0 / 5.0 / 20.0.

#define N_SENS 10000
#define N_HID  400000
#define N_MOT  1000

// mem = 0.9*mem_in + scale*inp ; spk = (mem - 1 > 0)
__global__ void lif_kernel(const float* __restrict__ inp,
                           const float* __restrict__ mem_in,
                           float* __restrict__ spk,
                           float scale, int n) {
    int i = blockIdx.x * blockDim.x + threadIdx.x;
    if (i < n) {
        float m = 0.9f * mem_in[i] + scale * inp[i];
        spk[i] = (m > 1.0f) ? 1.0f : 0.0f;
    }
}

// out[post[e]] += scale * w[e] * spikes[pre[e]]  (skip inactive pre to save
// the w/post loads -- big win for the 5%-active hh layer)
__global__ void scatter_kernel(const int* __restrict__ pre,
                               const int* __restrict__ post,
                               const float* __restrict__ w,
                               const float* __restrict__ spikes,
                               float* __restrict__ out,
                               float scale, int n_edges) {
    int e = blockIdx.x * blockDim.x + threadIdx.x;
    if (e < n_edges) {
        float s = spikes[pre[e]];
        if (s != 0.0f) {
            atomicAdd(&out[post[e]], scale * w[e] * s);
        }
    }
}

extern "C" void kernel_launch(void* const* d_in, const int* in_sizes, int n_in,
                              void* d_out, int out_size, void* d_ws, size_t ws_size,
                              hipStream_t stream) {
    const float* sensory_input = (const float*)d_in[0];
    const float* sensory_mem   = (const float*)d_in[1];
    const float* hidden_mem    = (const float*)d_in[2];
    const float* motor_mem     = (const float*)d_in[3];
    const float* hidden_prev   = (const float*)d_in[4];
    const float* w_sh          = (const float*)d_in[5];
    const float* w_hh          = (const float*)d_in[6];
    const float* w_hm          = (const float*)d_in[7];
    const int*   sh_pre        = (const int*)d_in[8];
    const int*   sh_post       = (const int*)d_in[9];
    const int*   hh_pre        = (const int*)d_in[10];
    const int*   hh_post       = (const int*)d_in[11];
    const int*   hm_pre        = (const int*)d_in[12];
    const int*   hm_post       = (const int*)d_in[13];
    const int e_sh = in_sizes[5];
    const int e_hh = in_sizes[6];
    const int e_hm = in_sizes[7];

    // workspace layout (floats): [sens_spk 10K][hid_in 400K][mot_in 1K][hid_spk 400K]
    float* ws       = (float*)d_ws;
    float* sens_spk = ws;
    float* hid_in   = sens_spk + N_SENS;
    float* mot_in   = hid_in + N_HID;
    float* hid_spk  = mot_in + N_MOT;

    // zero the accumulators (hid_in + mot_in are contiguous)
    hipMemsetAsync(hid_in, 0, (size_t)(N_HID + N_MOT) * sizeof(float), stream);

    const int B = 256;
    lif_kernel<<<(N_SENS + B - 1) / B, B, 0, stream>>>(sensory_input, sensory_mem,
                                                       sens_spk, 5.0f, N_SENS);
    scatter_kernel<<<(e_sh + B - 1) / B, B, 0, stream>>>(sh_pre, sh_post, w_sh,
                                                         sens_spk, hid_in, 1.0f, e_sh);
    scatter_kernel<<<(e_hh + B - 1) / B, B, 0, stream>>>(hh_pre, hh_post, w_hh,
                                                         hidden_prev, hid_in, 0.5f, e_hh);
    lif_kernel<<<(N_HID + B - 1) / B, B, 0, stream>>>(hid_in, hidden_mem,
                                                      hid_spk, 5.0f, N_HID);
    scatter_kernel<<<(e_hm + B - 1) / B, B, 0, stream>>>(hm_pre, hm_post, w_hm,
                                                         hid_spk, mot_in, 1.0f, e_hm);
    lif_kernel<<<(N_MOT + B - 1) / B, B, 0, stream>>>(mot_in, motor_mem,
                                                      (float*)d_out, 20.0f, N_MOT);
}